// Round 5
// baseline (781.138 us; speedup 1.0000x reference)
//
#include <hip/hip_runtime.h>
#include <math.h>

#define PHASE_K  0.3490658503988659f   // PI / 9.0
#define NPASS 8

// sin/cos via short Taylor series — valid for |x| <= 0.035 rad (guaranteed:
// rel_emb in [-0.1,0.1], scaled by pi/9). Max err ~4e-10.
__device__ __forceinline__ void tiny_sincos(float x, float* s, float* c) {
    float t = x * x;
    *s = x * fmaf(t, -1.0f / 6.0f, 1.0f);                      // x - x^3/6
    *c = fmaf(t, fmaf(t, 1.0f / 24.0f, -0.5f), 1.0f);          // 1 - x^2/2 + x^4/24
}

// One 64-lane wave handles 4 consecutive edges, processing only those whose
// HEAD node falls in [lo,hi). 8 sequential passes cover all heads; within a
// pass the head slice (~25.6 MB) stays L3-hot, eliminating head-gather misses.
__global__ __launch_bounds__(256) void rotate_score_pass(
    const float* __restrict__ node,     // [nnodes, 512]
    const int*   __restrict__ eidx,     // [2, nedges] flat
    const int*   __restrict__ rel,      // [nedges]
    const float* __restrict__ rel_emb,  // [64, 256]
    const float* __restrict__ temp,     // scalar
    const float* __restrict__ bias,     // scalar
    float*       __restrict__ out,      // [nedges]
    int nedges, int lo, int hi)
{
    int wid  = threadIdx.x >> 6;
    int lane = threadIdx.x & 63;
    int e0 = __builtin_amdgcn_readfirstlane((blockIdx.x * 4 + wid) * 4);
    if (e0 >= nedges) return;

    // Head indices of the wave's 4 edges — wave-uniform scalar loads.
    int last = nedges - 1;
    int h0 = __builtin_amdgcn_readfirstlane(eidx[min(e0 + 0, last)]);
    int h1 = __builtin_amdgcn_readfirstlane(eidx[min(e0 + 1, last)]);
    int h2 = __builtin_amdgcn_readfirstlane(eidx[min(e0 + 2, last)]);
    int h3 = __builtin_amdgcn_readfirstlane(eidx[min(e0 + 3, last)]);

    int d = lane << 2;                   // dim offset in [0,256), step 4

    #pragma unroll
    for (int k = 0; k < 4; ++k) {
        int h = (k == 0) ? h0 : (k == 1) ? h1 : (k == 2) ? h2 : h3;
        int e = e0 + k;
        if (h < lo || h >= hi || e >= nedges) continue;   // wave-uniform branch

        int t = __builtin_amdgcn_readfirstlane(eidx[nedges + e]);
        int r = __builtin_amdgcn_readfirstlane(rel[e]);

        const float4* ph = (const float4*)(node + (size_t)h * 512 + d);
        const float4* pt = (const float4*)(node + (size_t)t * 512 + d);
        float4 rh = ph[0];               // re(head)
        float4 ih = ph[64];              // im(head): +256 floats
        float4 rt = pt[0];
        float4 it = pt[64];
        float4 pe = *(const float4*)(rel_emb + (r << 8) + d);

        float cx, sx, cy, sy, cz, sz, cw, sw;
        tiny_sincos(pe.x * PHASE_K, &sx, &cx);
        tiny_sincos(pe.y * PHASE_K, &sy, &cy);
        tiny_sincos(pe.z * PHASE_K, &sz, &cz);
        tiny_sincos(pe.w * PHASE_K, &sw, &cw);

        float sum;
        {
            float rd, id;
            rd = fmaf(rh.x, cx, -fmaf(ih.x, sx, rt.x));
            id = fmaf(rh.x, sx,  fmaf(ih.x, cx, -it.x));
            sum  = __builtin_amdgcn_sqrtf(fmaf(rd, rd, id * id));
            rd = fmaf(rh.y, cy, -fmaf(ih.y, sy, rt.y));
            id = fmaf(rh.y, sy,  fmaf(ih.y, cy, -it.y));
            sum += __builtin_amdgcn_sqrtf(fmaf(rd, rd, id * id));
            rd = fmaf(rh.z, cz, -fmaf(ih.z, sz, rt.z));
            id = fmaf(rh.z, sz,  fmaf(ih.z, cz, -it.z));
            sum += __builtin_amdgcn_sqrtf(fmaf(rd, rd, id * id));
            rd = fmaf(rh.w, cw, -fmaf(ih.w, sw, rt.w));
            id = fmaf(rh.w, sw,  fmaf(ih.w, cw, -it.w));
            sum += __builtin_amdgcn_sqrtf(fmaf(rd, rd, id * id));
        }

        #pragma unroll
        for (int m = 1; m < 64; m <<= 1)
            sum += __shfl_xor(sum, m);

        if (lane == 0) {
            float T = temp[0];
            float B = bias[0];
            out[e] = B - (sum * (1.0f / 256.0f)) / T;
        }
    }
}

extern "C" void kernel_launch(void* const* d_in, const int* in_sizes, int n_in,
                              void* d_out, int out_size, void* d_ws, size_t ws_size,
                              hipStream_t stream) {
    const float* node    = (const float*)d_in[0];
    const int*   eidx    = (const int*)  d_in[1];
    const int*   rel     = (const int*)  d_in[2];
    const float* rel_emb = (const float*)d_in[3];
    const float* temp    = (const float*)d_in[4];
    const float* bias    = (const float*)d_in[5];
    float*       out     = (float*)d_out;

    int nedges = in_sizes[1] / 2;        // edge_index is [2, nedges]
    int nnodes = in_sizes[0] / 512;      // 100000

    int blocks = (nedges + 15) / 16;     // 4 waves/block x 4 edges/wave
    for (int p = 0; p < NPASS; ++p) {
        int lo = (int)(( (long long)p      * nnodes) / NPASS);
        int hi = (int)(( (long long)(p + 1) * nnodes) / NPASS);
        rotate_score_pass<<<blocks, 256, 0, stream>>>(
            node, eidx, rel, rel_emb, temp, bias, out, nedges, lo, hi);
    }
}

// Round 6
// 586.030 us; speedup vs baseline: 1.3329x; 1.3329x over previous
//
#include <hip/hip_runtime.h>
#include <math.h>

#define PHASE_K  0.3490658503988659f   // PI / 9.0

// sin/cos via short Taylor series — valid for |x| <= 0.035 rad (guaranteed:
// rel_emb in [-0.1,0.1], scaled by pi/9). Max err ~4e-10.
__device__ __forceinline__ void tiny_sincos(float x, float* s, float* c) {
    float t = x * x;
    *s = x * fmaf(t, -1.0f / 6.0f, 1.0f);                 // x - x^3/6
    *c = fmaf(t, fmaf(t, 1.0f / 24.0f, -0.5f), 1.0f);     // 1 - x^2/2 + x^4/24
}

__device__ __forceinline__ unsigned int f2bf_rne(float f) {   // fp32 -> bf16 (RNE)
    unsigned int u = __float_as_uint(f);
    return (u + 0x7FFFu + ((u >> 16) & 1u)) >> 16;
}
__device__ __forceinline__ float bf2f(unsigned int us) {      // bf16 (low 16) -> fp32
    return __uint_as_float(us << 16);
}

// Convert node table fp32 [n][512] (re block | im block) into interleaved bf16:
// word j of node n = (im[j]<<16 | re[j]). 256 uint words (1 KB) per node.
// One thread per 4 complex dims; wave covers one node row.
__global__ __launch_bounds__(256) void convert_kernel(
    const float* __restrict__ node, unsigned int* __restrict__ tbl, int nnodes)
{
    int p = blockIdx.x * 256 + threadIdx.x;          // [0, nnodes*64)
    if (p >= nnodes * 64) return;
    int n = p >> 6, q = p & 63;
    const float4 re = *(const float4*)(node + (size_t)n * 512 + 4 * q);
    const float4 im = *(const float4*)(node + (size_t)n * 512 + 256 + 4 * q);
    uint4 w;
    w.x = f2bf_rne(re.x) | (f2bf_rne(im.x) << 16);
    w.y = f2bf_rne(re.y) | (f2bf_rne(im.y) << 16);
    w.z = f2bf_rne(re.z) | (f2bf_rne(im.z) << 16);
    w.w = f2bf_rne(re.w) | (f2bf_rne(im.w) << 16);
    *(uint4*)(tbl + (size_t)n * 256 + 4 * q) = w;
}

// One 64-lane wave per edge; lane handles complex dims [4*lane, 4*lane+4).
// Head/tail rows read as 16 B from the interleaved bf16 table (L3-resident).
__global__ __launch_bounds__(256) void rotate_score_bf16(
    const unsigned int* __restrict__ tbl,   // [nnodes][256] words
    const int*   __restrict__ eidx,         // [2, nedges] flat
    const int*   __restrict__ rel,          // [nedges]
    const float* __restrict__ rel_emb,      // [64, 256]
    const float* __restrict__ temp,
    const float* __restrict__ bias,
    float*       __restrict__ out,
    int nedges)
{
    int gtid = blockIdx.x * 256 + threadIdx.x;
    int edge = gtid >> 6;
    int lane = threadIdx.x & 63;
    if (edge >= nedges) return;

    int e_u = __builtin_amdgcn_readfirstlane(edge);
    int h = __builtin_amdgcn_readfirstlane(eidx[e_u]);
    int t = __builtin_amdgcn_readfirstlane(eidx[nedges + e_u]);
    int r = __builtin_amdgcn_readfirstlane(rel[e_u]);

    uint4 hw = *(const uint4*)(tbl + (size_t)h * 256 + 4 * lane);
    uint4 tw = *(const uint4*)(tbl + (size_t)t * 256 + 4 * lane);
    float4 pe = *(const float4*)(rel_emb + (r << 8) + (lane << 2));

    float sum = 0.0f;
    {
        float c, s, rd, id, rh, ih, rt, it;

        rh = bf2f(hw.x & 0xFFFFu); ih = bf2f(hw.x >> 16);
        rt = bf2f(tw.x & 0xFFFFu); it = bf2f(tw.x >> 16);
        tiny_sincos(pe.x * PHASE_K, &s, &c);
        rd = fmaf(rh, c, -fmaf(ih, s, rt));
        id = fmaf(rh, s,  fmaf(ih, c, -it));
        sum += __builtin_amdgcn_sqrtf(fmaf(rd, rd, id * id));

        rh = bf2f(hw.y & 0xFFFFu); ih = bf2f(hw.y >> 16);
        rt = bf2f(tw.y & 0xFFFFu); it = bf2f(tw.y >> 16);
        tiny_sincos(pe.y * PHASE_K, &s, &c);
        rd = fmaf(rh, c, -fmaf(ih, s, rt));
        id = fmaf(rh, s,  fmaf(ih, c, -it));
        sum += __builtin_amdgcn_sqrtf(fmaf(rd, rd, id * id));

        rh = bf2f(hw.z & 0xFFFFu); ih = bf2f(hw.z >> 16);
        rt = bf2f(tw.z & 0xFFFFu); it = bf2f(tw.z >> 16);
        tiny_sincos(pe.z * PHASE_K, &s, &c);
        rd = fmaf(rh, c, -fmaf(ih, s, rt));
        id = fmaf(rh, s,  fmaf(ih, c, -it));
        sum += __builtin_amdgcn_sqrtf(fmaf(rd, rd, id * id));

        rh = bf2f(hw.w & 0xFFFFu); ih = bf2f(hw.w >> 16);
        rt = bf2f(tw.w & 0xFFFFu); it = bf2f(tw.w >> 16);
        tiny_sincos(pe.w * PHASE_K, &s, &c);
        rd = fmaf(rh, c, -fmaf(ih, s, rt));
        id = fmaf(rh, s,  fmaf(ih, c, -it));
        sum += __builtin_amdgcn_sqrtf(fmaf(rd, rd, id * id));
    }

    #pragma unroll
    for (int m = 1; m < 64; m <<= 1)
        sum += __shfl_xor(sum, m);

    if (lane == 0)
        out[edge] = bias[0] - (sum * (1.0f / 256.0f)) / temp[0];
}

// Fallback: direct fp32 gather (round-2 kernel) if workspace is too small.
__global__ __launch_bounds__(256) void rotate_score_fp32(
    const float* __restrict__ node, const int* __restrict__ eidx,
    const int* __restrict__ rel, const float* __restrict__ rel_emb,
    const float* __restrict__ temp, const float* __restrict__ bias,
    float* __restrict__ out, int nedges)
{
    int gtid = blockIdx.x * 256 + threadIdx.x;
    int edge = gtid >> 6;
    int lane = threadIdx.x & 63;
    if (edge >= nedges) return;

    int e_u = __builtin_amdgcn_readfirstlane(edge);
    int h = __builtin_amdgcn_readfirstlane(eidx[e_u]);
    int t = __builtin_amdgcn_readfirstlane(eidx[nedges + e_u]);
    int r = __builtin_amdgcn_readfirstlane(rel[e_u]);
    int d = lane << 2;

    const float4* ph = (const float4*)(node + (size_t)h * 512 + d);
    const float4* pt = (const float4*)(node + (size_t)t * 512 + d);
    float4 rh = ph[0], ih = ph[64], rt = pt[0], it = pt[64];
    float4 pe = *(const float4*)(rel_emb + (r << 8) + d);

    float cx, sx, cy, sy, cz, sz, cw, sw;
    tiny_sincos(pe.x * PHASE_K, &sx, &cx);
    tiny_sincos(pe.y * PHASE_K, &sy, &cy);
    tiny_sincos(pe.z * PHASE_K, &sz, &cz);
    tiny_sincos(pe.w * PHASE_K, &sw, &cw);

    float sum, rd, id;
    rd = fmaf(rh.x, cx, -fmaf(ih.x, sx, rt.x));
    id = fmaf(rh.x, sx,  fmaf(ih.x, cx, -it.x));
    sum  = __builtin_amdgcn_sqrtf(fmaf(rd, rd, id * id));
    rd = fmaf(rh.y, cy, -fmaf(ih.y, sy, rt.y));
    id = fmaf(rh.y, sy,  fmaf(ih.y, cy, -it.y));
    sum += __builtin_amdgcn_sqrtf(fmaf(rd, rd, id * id));
    rd = fmaf(rh.z, cz, -fmaf(ih.z, sz, rt.z));
    id = fmaf(rh.z, sz,  fmaf(ih.z, cz, -it.z));
    sum += __builtin_amdgcn_sqrtf(fmaf(rd, rd, id * id));
    rd = fmaf(rh.w, cw, -fmaf(ih.w, sw, rt.w));
    id = fmaf(rh.w, sw,  fmaf(ih.w, cw, -it.w));
    sum += __builtin_amdgcn_sqrtf(fmaf(rd, rd, id * id));

    #pragma unroll
    for (int m = 1; m < 64; m <<= 1)
        sum += __shfl_xor(sum, m);

    if (lane == 0)
        out[edge] = bias[0] - (sum * (1.0f / 256.0f)) / temp[0];
}

extern "C" void kernel_launch(void* const* d_in, const int* in_sizes, int n_in,
                              void* d_out, int out_size, void* d_ws, size_t ws_size,
                              hipStream_t stream) {
    const float* node    = (const float*)d_in[0];
    const int*   eidx    = (const int*)  d_in[1];
    const int*   rel     = (const int*)  d_in[2];
    const float* rel_emb = (const float*)d_in[3];
    const float* temp    = (const float*)d_in[4];
    const float* bias    = (const float*)d_in[5];
    float*       out     = (float*)d_out;

    int nedges = in_sizes[1] / 2;        // edge_index is [2, nedges]
    int nnodes = in_sizes[0] / 512;      // 100000

    int eblocks = (nedges + 3) / 4;      // 4 waves (edges) per 256-thread block
    size_t need = (size_t)nnodes * 1024; // interleaved bf16 table bytes

    if (ws_size >= need) {
        unsigned int* tbl = (unsigned int*)d_ws;
        int cblocks = (nnodes * 64 + 255) / 256;
        convert_kernel<<<cblocks, 256, 0, stream>>>(node, tbl, nnodes);
        rotate_score_bf16<<<eblocks, 256, 0, stream>>>(
            tbl, eidx, rel, rel_emb, temp, bias, out, nedges);
    } else {
        rotate_score_fp32<<<eblocks, 256, 0, stream>>>(
            node, eidx, rel, rel_emb, temp, bias, out, nedges);
    }
}

// Round 9
// 556.423 us; speedup vs baseline: 1.4039x; 1.0532x over previous
//
#include <hip/hip_runtime.h>
#include <math.h>

#define PHASE_K  0.3490658503988659f   // PI / 9.0

// sin/cos via short Taylor series — valid for |x| <= 0.035 rad (guaranteed:
// rel_emb in [-0.1,0.1], scaled by pi/9). Max err ~4e-10.
__device__ __forceinline__ void tiny_sincos(float x, float* s, float* c) {
    float t = x * x;
    *s = x * fmaf(t, -1.0f / 6.0f, 1.0f);                 // x - x^3/6
    *c = fmaf(t, fmaf(t, 1.0f / 24.0f, -0.5f), 1.0f);     // 1 - x^2/2 + x^4/24
}

__device__ __forceinline__ unsigned int f2bf_rne(float f) {   // fp32 -> bf16 (RNE)
    unsigned int u = __float_as_uint(f);
    return (u + 0x7FFFu + ((u >> 16) & 1u)) >> 16;
}

// ---- pre-pass 1: rotation table [64][256] words = (sin_bf16<<16)|cos_bf16 ----
__global__ __launch_bounds__(256) void build_rot_kernel(
    const float* __restrict__ rel_emb, unsigned int* __restrict__ rot, int n)
{
    int i = blockIdx.x * 256 + threadIdx.x;
    if (i >= n) return;
    float s, c;
    tiny_sincos(rel_emb[i] * PHASE_K, &s, &c);
    rot[i] = (f2bf_rne(s) << 16) | f2bf_rne(c);
}

// ---- pre-pass 2: node table fp32 [n][512] -> interleaved bf16 (im<<16|re) ----
__global__ __launch_bounds__(256) void convert_kernel(
    const float* __restrict__ node, unsigned int* __restrict__ tbl, int nnodes)
{
    int p = blockIdx.x * 256 + threadIdx.x;          // [0, nnodes*64)
    if (p >= nnodes * 64) return;
    int n = p >> 6, q = p & 63;
    const float4 re = *(const float4*)(node + (size_t)n * 512 + 4 * q);
    const float4 im = *(const float4*)(node + (size_t)n * 512 + 256 + 4 * q);
    uint4 w;
    w.x = f2bf_rne(re.x) | (f2bf_rne(im.x) << 16);
    w.y = f2bf_rne(re.y) | (f2bf_rne(im.y) << 16);
    w.z = f2bf_rne(re.z) | (f2bf_rne(im.z) << 16);
    w.w = f2bf_rne(re.w) | (f2bf_rne(im.w) << 16);
    *(uint4*)(tbl + (size_t)n * 256 + 4 * q) = w;
}

// one complex dim: hw/tw = (im<<16|re) bf16 pair, rw = (sin<<16|cos)
__device__ __forceinline__ float dim_term(unsigned int hw, unsigned int tw,
                                          unsigned int rw) {
    float rh = __uint_as_float(hw << 16);
    float ih = __uint_as_float(hw & 0xFFFF0000u);
    float rt = __uint_as_float(tw << 16);
    float it = __uint_as_float(tw & 0xFFFF0000u);
    float c  = __uint_as_float(rw << 16);
    float s  = __uint_as_float(rw & 0xFFFF0000u);
    float rd = fmaf(rh, c, -fmaf(ih, s, rt));
    float id = fmaf(rh, s,  fmaf(ih, c, -it));
    return __builtin_amdgcn_sqrtf(fmaf(rd, rd, id * id));
}

// DPP row_shr:K inclusive-scan step; after K=1,2,4,8 lane15 of each row16 has the sum.
template <int CTRL>
__device__ __forceinline__ float dpp_shr_add(float x) {
    int y = __builtin_amdgcn_update_dpp(0, __float_as_int(x), CTRL, 0xF, 0xF, true);
    return x + __int_as_float(y);
}

// ---- main: 16 lanes per edge; lane handles 16 complex dims (stride-64 words) ----
__global__ __launch_bounds__(256) void rotate_score_v3(
    const unsigned int* __restrict__ tbl,   // [nnodes][256] words
    const unsigned int* __restrict__ rot,   // [64][256] words
    const int*   __restrict__ eidx,         // [2, nedges] flat
    const int*   __restrict__ rel,          // [nedges]
    const float* __restrict__ temp,
    const float* __restrict__ bias,
    float*       __restrict__ out,
    int nedges)
{
    int gtid = blockIdx.x * 256 + threadIdx.x;
    int edge = gtid >> 4;
    int sub  = threadIdx.x & 15;
    if (edge >= nedges) return;

    int h = eidx[edge];
    int t = eidx[nedges + edge];
    int r = rel[edge];

    const unsigned int* ph = tbl + (size_t)h * 256 + 4 * sub;
    const unsigned int* pt = tbl + (size_t)t * 256 + 4 * sub;
    const unsigned int* pr = rot + (r << 8) + 4 * sub;

    // 12 x dwordx4 loads issued up front (MLP); dims covered: 4*sub + 64*j + {0..3}
    uint4 h0 = *(const uint4*)(ph);
    uint4 h1 = *(const uint4*)(ph + 64);
    uint4 h2 = *(const uint4*)(ph + 128);
    uint4 h3 = *(const uint4*)(ph + 192);
    uint4 t0 = *(const uint4*)(pt);
    uint4 t1 = *(const uint4*)(pt + 64);
    uint4 t2 = *(const uint4*)(pt + 128);
    uint4 t3 = *(const uint4*)(pt + 192);
    uint4 r0 = *(const uint4*)(pr);
    uint4 r1 = *(const uint4*)(pr + 64);
    uint4 r2 = *(const uint4*)(pr + 128);
    uint4 r3 = *(const uint4*)(pr + 192);

    float sum = 0.0f;
    sum += dim_term(h0.x, t0.x, r0.x);
    sum += dim_term(h0.y, t0.y, r0.y);
    sum += dim_term(h0.z, t0.z, r0.z);
    sum += dim_term(h0.w, t0.w, r0.w);
    sum += dim_term(h1.x, t1.x, r1.x);
    sum += dim_term(h1.y, t1.y, r1.y);
    sum += dim_term(h1.z, t1.z, r1.z);
    sum += dim_term(h1.w, t1.w, r1.w);
    sum += dim_term(h2.x, t2.x, r2.x);
    sum += dim_term(h2.y, t2.y, r2.y);
    sum += dim_term(h2.z, t2.z, r2.z);
    sum += dim_term(h2.w, t2.w, r2.w);
    sum += dim_term(h3.x, t3.x, r3.x);
    sum += dim_term(h3.y, t3.y, r3.y);
    sum += dim_term(h3.z, t3.z, r3.z);
    sum += dim_term(h3.w, t3.w, r3.w);

    sum = dpp_shr_add<0x111>(sum);   // row_shr:1
    sum = dpp_shr_add<0x112>(sum);   // row_shr:2
    sum = dpp_shr_add<0x114>(sum);   // row_shr:4
    sum = dpp_shr_add<0x118>(sum);   // row_shr:8 -> lane15 of each row16 = total

    if (sub == 15)
        out[edge] = bias[0] - (sum * (1.0f / 256.0f)) / temp[0];
}

// Fallback: direct fp32 gather (round-2 kernel) if workspace is too small.
__global__ __launch_bounds__(256) void rotate_score_fp32(
    const float* __restrict__ node, const int* __restrict__ eidx,
    const int* __restrict__ rel, const float* __restrict__ rel_emb,
    const float* __restrict__ temp, const float* __restrict__ bias,
    float* __restrict__ out, int nedges)
{
    int gtid = blockIdx.x * 256 + threadIdx.x;
    int edge = gtid >> 6;
    int lane = threadIdx.x & 63;
    if (edge >= nedges) return;

    int e_u = __builtin_amdgcn_readfirstlane(edge);
    int h = __builtin_amdgcn_readfirstlane(eidx[e_u]);
    int t = __builtin_amdgcn_readfirstlane(eidx[nedges + e_u]);
    int r = __builtin_amdgcn_readfirstlane(rel[e_u]);
    int d = lane << 2;

    const float4* ph = (const float4*)(node + (size_t)h * 512 + d);
    const float4* pt = (const float4*)(node + (size_t)t * 512 + d);
    float4 rh = ph[0], ih = ph[64], rt = pt[0], it = pt[64];
    float4 pe = *(const float4*)(rel_emb + (r << 8) + d);

    float cx, sx, cy, sy, cz, sz, cw, sw;
    tiny_sincos(pe.x * PHASE_K, &sx, &cx);
    tiny_sincos(pe.y * PHASE_K, &sy, &cy);
    tiny_sincos(pe.z * PHASE_K, &sz, &cz);
    tiny_sincos(pe.w * PHASE_K, &sw, &cw);

    float sum, rd, id;
    rd = fmaf(rh.x, cx, -fmaf(ih.x, sx, rt.x));
    id = fmaf(rh.x, sx,  fmaf(ih.x, cx, -it.x));
    sum  = __builtin_amdgcn_sqrtf(fmaf(rd, rd, id * id));
    rd = fmaf(rh.y, cy, -fmaf(ih.y, sy, rt.y));
    id = fmaf(rh.y, sy,  fmaf(ih.y, cy, -it.y));
    sum += __builtin_amdgcn_sqrtf(fmaf(rd, rd, id * id));
    rd = fmaf(rh.z, cz, -fmaf(ih.z, sz, rt.z));
    id = fmaf(rh.z, sz,  fmaf(ih.z, cz, -it.z));
    sum += __builtin_amdgcn_sqrtf(fmaf(rd, rd, id * id));
    rd = fmaf(rh.w, cw, -fmaf(ih.w, sw, rt.w));
    id = fmaf(rh.w, sw,  fmaf(ih.w, cw, -it.w));
    sum += __builtin_amdgcn_sqrtf(fmaf(rd, rd, id * id));

    #pragma unroll
    for (int m = 1; m < 64; m <<= 1)
        sum += __shfl_xor(sum, m);

    if (lane == 0)
        out[edge] = bias[0] - (sum * (1.0f / 256.0f)) / temp[0];
}

extern "C" void kernel_launch(void* const* d_in, const int* in_sizes, int n_in,
                              void* d_out, int out_size, void* d_ws, size_t ws_size,
                              hipStream_t stream) {
    const float* node    = (const float*)d_in[0];
    const int*   eidx    = (const int*)  d_in[1];
    const int*   rel     = (const int*)  d_in[2];
    const float* rel_emb = (const float*)d_in[3];
    const float* temp    = (const float*)d_in[4];
    const float* bias    = (const float*)d_in[5];
    float*       out     = (float*)d_out;

    int nedges = in_sizes[1] / 2;        // edge_index is [2, nedges]
    int nnodes = in_sizes[0] / 512;      // 100000
    int nrot   = in_sizes[3];            // 64*256 = 16384

    size_t tbl_bytes = (size_t)nnodes * 1024;          // bf16 node table
    size_t need      = tbl_bytes + (size_t)nrot * 4;   // + rot table

    if (ws_size >= need) {
        unsigned int* tbl = (unsigned int*)d_ws;
        unsigned int* rot = (unsigned int*)((char*)d_ws + tbl_bytes);

        build_rot_kernel<<<(nrot + 255) / 256, 256, 0, stream>>>(rel_emb, rot, nrot);

        int cblocks = (nnodes * 64 + 255) / 256;
        convert_kernel<<<cblocks, 256, 0, stream>>>(node, tbl, nnodes);

        int gblocks = (nedges * 16 + 255) / 256;       // 16 lanes per edge
        rotate_score_v3<<<gblocks, 256, 0, stream>>>(
            tbl, rot, eidx, rel, temp, bias, out, nedges);
    } else {
        int eblocks = (nedges + 3) / 4;
        rotate_score_fp32<<<eblocks, 256, 0, stream>>>(
            node, eidx, rel, rel_emb, temp, bias, out, nedges);
    }
}

// Round 12
// 544.082 us; speedup vs baseline: 1.4357x; 1.0227x over previous
//
#include <hip/hip_runtime.h>
#include <math.h>

#define PHASE_K  0.3490658503988659f   // PI / 9.0

__device__ __forceinline__ void tiny_sincos(float x, float* s, float* c) {
    float t = x * x;
    *s = x * fmaf(t, -1.0f / 6.0f, 1.0f);                 // x - x^3/6
    *c = fmaf(t, fmaf(t, 1.0f / 24.0f, -0.5f), 1.0f);     // 1 - x^2/2 + x^4/24
}

__device__ __forceinline__ unsigned int f2bf_rne(float f) {   // fp32 -> bf16 (RNE)
    unsigned int u = __float_as_uint(f);
    return (u + 0x7FFFu + ((u >> 16) & 1u)) >> 16;
}

// ---- pre-pass 1: rotation table [64][256] words = (sin_bf16<<16)|cos_bf16 ----
__global__ __launch_bounds__(256) void build_rot_kernel(
    const float* __restrict__ rel_emb, unsigned int* __restrict__ rot, int n)
{
    int i = blockIdx.x * 256 + threadIdx.x;
    if (i >= n) return;
    float s, c;
    tiny_sincos(rel_emb[i] * PHASE_K, &s, &c);
    rot[i] = (f2bf_rne(s) << 16) | f2bf_rne(c);
}

// ---- pre-pass 2: node rows -> 12-bit per-row-scaled packed table ----
// Row = 256 complex dims x 3 B = 768 B (192 words). Dim j in its 12-B group:
// B[3j]=re_hi8, B[3j+1]=im_hi8, B[3j+2]=(re_lo4)|(im_lo4<<4), u = q+2048.
// One 64-lane wave per node row; lane handles dims [4*lane, 4*lane+4).
__global__ __launch_bounds__(256) void convert12_kernel(
    const float* __restrict__ node, unsigned int* __restrict__ tbl,
    float* __restrict__ scl, int nnodes)
{
    int wid  = (blockIdx.x * 256 + threadIdx.x) >> 6;   // node id
    int lane = threadIdx.x & 63;
    if (wid >= nnodes) return;

    const float* row = node + (size_t)wid * 512;
    float4 re = *(const float4*)(row + 4 * lane);
    float4 im = *(const float4*)(row + 256 + 4 * lane);

    float m = fmaxf(fmaxf(fabsf(re.x), fabsf(re.y)), fmaxf(fabsf(re.z), fabsf(re.w)));
    m = fmaxf(m, fmaxf(fmaxf(fabsf(im.x), fabsf(im.y)), fmaxf(fabsf(im.z), fabsf(im.w))));
    #pragma unroll
    for (int k = 1; k < 64; k <<= 1) m = fmaxf(m, __shfl_xor(m, k));
    m = fmaxf(m, 1e-20f);
    float inv = 2047.0f / m;

    float rv[4] = {re.x, re.y, re.z, re.w};
    float iv[4] = {im.x, im.y, im.z, im.w};
    unsigned int ur[4], ui[4];
    #pragma unroll
    for (int j = 0; j < 4; ++j) {
        ur[j] = (unsigned int)((int)rintf(rv[j] * inv) + 2048);
        ui[j] = (unsigned int)((int)rintf(iv[j] * inv) + 2048);
    }
    unsigned int B[12];
    #pragma unroll
    for (int j = 0; j < 4; ++j) {
        B[3*j]   = (ur[j] >> 4) & 0xFFu;
        B[3*j+1] = (ui[j] >> 4) & 0xFFu;
        B[3*j+2] = (ur[j] & 0xFu) | ((ui[j] & 0xFu) << 4);
    }
    unsigned int w0 = B[0] | (B[1] << 8) | (B[2]  << 16) | (B[3]  << 24);
    unsigned int w1 = B[4] | (B[5] << 8) | (B[6]  << 16) | (B[7]  << 24);
    unsigned int w2 = B[8] | (B[9] << 8) | (B[10] << 16) | (B[11] << 24);

    unsigned int* dst = tbl + (size_t)wid * 192 + 3 * lane;
    dst[0] = w0; dst[1] = w1; dst[2] = w2;
    if (lane == 0) scl[wid] = m * (1.0f / 2047.0f);
}

// one complex dim from unpacked 12-bit codes + packed rot word
__device__ __forceinline__ float dim_term12(
    unsigned int uhr, unsigned int uhi, unsigned int utr, unsigned int uti,
    unsigned int rw, float sh, float oh, float st, float ot)
{
    float rh = fmaf((float)uhr, sh, oh);
    float ih = fmaf((float)uhi, sh, oh);
    float rt = fmaf((float)utr, st, ot);
    float it = fmaf((float)uti, st, ot);
    float c  = __uint_as_float(rw << 16);
    float s  = __uint_as_float(rw & 0xFFFF0000u);
    float rd = fmaf(rh, c, -fmaf(ih, s, rt));
    float id = fmaf(rh, s,  fmaf(ih, c, -it));
    return __builtin_amdgcn_sqrtf(fmaf(rd, rd, id * id));
}

// unpack one 12-B group (w0,w1,w2 = 4 dims) for head+tail and accumulate
__device__ __forceinline__ float group_terms(
    unsigned int hw0, unsigned int hw1, unsigned int hw2,
    unsigned int tw0, unsigned int tw1, unsigned int tw2,
    uint4 R, float sh, float oh, float st, float ot)
{
    float acc;
    acc  = dim_term12(((hw0 & 255u) << 4) | ((hw0 >> 16) & 15u),
                      (((hw0 >> 8) & 255u) << 4) | ((hw0 >> 20) & 15u),
                      ((tw0 & 255u) << 4) | ((tw0 >> 16) & 15u),
                      (((tw0 >> 8) & 255u) << 4) | ((tw0 >> 20) & 15u),
                      R.x, sh, oh, st, ot);
    acc += dim_term12(((hw0 >> 24) << 4) | ((hw1 >> 8) & 15u),
                      ((hw1 & 255u) << 4) | ((hw1 >> 12) & 15u),
                      ((tw0 >> 24) << 4) | ((tw1 >> 8) & 15u),
                      ((tw1 & 255u) << 4) | ((tw1 >> 12) & 15u),
                      R.y, sh, oh, st, ot);
    acc += dim_term12((((hw1 >> 16) & 255u) << 4) | (hw2 & 15u),
                      ((hw1 >> 24) << 4) | ((hw2 >> 4) & 15u),
                      (((tw1 >> 16) & 255u) << 4) | (tw2 & 15u),
                      ((tw1 >> 24) << 4) | ((tw2 >> 4) & 15u),
                      R.z, sh, oh, st, ot);
    acc += dim_term12((((hw2 >> 8) & 255u) << 4) | ((hw2 >> 24) & 15u),
                      (((hw2 >> 16) & 255u) << 4) | (hw2 >> 28),
                      (((tw2 >> 8) & 255u) << 4) | ((tw2 >> 24) & 15u),
                      (((tw2 >> 16) & 255u) << 4) | (tw2 >> 28),
                      R.w, sh, oh, st, ot);
    return acc;
}

template <int CTRL>
__device__ __forceinline__ float dpp_shr_add(float x) {
    int y = __builtin_amdgcn_update_dpp(0, __float_as_int(x), CTRL, 0xF, 0xF, true);
    return x + __int_as_float(y);
}

// ---- main: 16 lanes per edge; lane handles dims [16*sub, 16*sub+16) ----
__global__ __launch_bounds__(256) void rotate_score_v4(
    const unsigned int* __restrict__ tbl,   // [nnodes][192] words
    const float*        __restrict__ scl,   // [nnodes]
    const unsigned int* __restrict__ rot,   // [64][256] words
    const int*   __restrict__ eidx,         // [2, nedges] flat
    const int*   __restrict__ rel,          // [nedges]
    const float* __restrict__ temp,
    const float* __restrict__ bias,
    float*       __restrict__ out,
    int nedges)
{
    int gtid = blockIdx.x * 256 + threadIdx.x;
    int edge = gtid >> 4;
    int sub  = threadIdx.x & 15;
    if (edge >= nedges) return;

    int h = eidx[edge];
    int t = eidx[nedges + edge];
    int r = rel[edge];

    const uint4* ph = (const uint4*)(tbl + (size_t)h * 192 + 12 * sub);
    const uint4* pt = (const uint4*)(tbl + (size_t)t * 192 + 12 * sub);
    const uint4* pr = (const uint4*)(rot + (r << 8) + 16 * sub);

    uint4 H0 = ph[0], H1 = ph[1], H2 = ph[2];
    uint4 T0 = pt[0], T1 = pt[1], T2 = pt[2];
    uint4 R0 = pr[0], R1 = pr[1], R2 = pr[2], R3 = pr[3];
    float sh = scl[h], st = scl[t];
    float oh = -2048.0f * sh, ot = -2048.0f * st;

    float sum;
    sum  = group_terms(H0.x, H0.y, H0.z,  T0.x, T0.y, T0.z,  R0, sh, oh, st, ot);
    sum += group_terms(H0.w, H1.x, H1.y,  T0.w, T1.x, T1.y,  R1, sh, oh, st, ot);
    sum += group_terms(H1.z, H1.w, H2.x,  T1.z, T1.w, T2.x,  R2, sh, oh, st, ot);
    sum += group_terms(H2.y, H2.z, H2.w,  T2.y, T2.z, T2.w,  R3, sh, oh, st, ot);

    sum = dpp_shr_add<0x111>(sum);   // row_shr:1
    sum = dpp_shr_add<0x112>(sum);   // row_shr:2
    sum = dpp_shr_add<0x114>(sum);   // row_shr:4
    sum = dpp_shr_add<0x118>(sum);   // row_shr:8 -> lane15 of each row16 = total

    if (sub == 15)
        out[edge] = bias[0] - (sum * (1.0f / 256.0f)) / temp[0];
}

// Fallback: direct fp32 gather if workspace is too small.
__global__ __launch_bounds__(256) void rotate_score_fp32(
    const float* __restrict__ node, const int* __restrict__ eidx,
    const int* __restrict__ rel, const float* __restrict__ rel_emb,
    const float* __restrict__ temp, const float* __restrict__ bias,
    float* __restrict__ out, int nedges)
{
    int gtid = blockIdx.x * 256 + threadIdx.x;
    int edge = gtid >> 6;
    int lane = threadIdx.x & 63;
    if (edge >= nedges) return;

    int e_u = __builtin_amdgcn_readfirstlane(edge);
    int h = __builtin_amdgcn_readfirstlane(eidx[e_u]);
    int t = __builtin_amdgcn_readfirstlane(eidx[nedges + e_u]);
    int r = __builtin_amdgcn_readfirstlane(rel[e_u]);
    int d = lane << 2;

    const float4* ph = (const float4*)(node + (size_t)h * 512 + d);
    const float4* pt = (const float4*)(node + (size_t)t * 512 + d);
    float4 rh = ph[0], ih = ph[64], rt = pt[0], it = pt[64];
    float4 pe = *(const float4*)(rel_emb + (r << 8) + d);

    float cx, sx, cy, sy, cz, sz, cw, sw;
    tiny_sincos(pe.x * PHASE_K, &sx, &cx);
    tiny_sincos(pe.y * PHASE_K, &sy, &cy);
    tiny_sincos(pe.z * PHASE_K, &sz, &cz);
    tiny_sincos(pe.w * PHASE_K, &sw, &cw);

    float sum, rd, id;
    rd = fmaf(rh.x, cx, -fmaf(ih.x, sx, rt.x));
    id = fmaf(rh.x, sx,  fmaf(ih.x, cx, -it.x));
    sum  = __builtin_amdgcn_sqrtf(fmaf(rd, rd, id * id));
    rd = fmaf(rh.y, cy, -fmaf(ih.y, sy, rt.y));
    id = fmaf(rh.y, sy,  fmaf(ih.y, cy, -it.y));
    sum += __builtin_amdgcn_sqrtf(fmaf(rd, rd, id * id));
    rd = fmaf(rh.z, cz, -fmaf(ih.z, sz, rt.z));
    id = fmaf(rh.z, sz,  fmaf(ih.z, cz, -it.z));
    sum += __builtin_amdgcn_sqrtf(fmaf(rd, rd, id * id));
    rd = fmaf(rh.w, cw, -fmaf(ih.w, sw, rt.w));
    id = fmaf(rh.w, sw,  fmaf(ih.w, cw, -it.w));
    sum += __builtin_amdgcn_sqrtf(fmaf(rd, rd, id * id));

    #pragma unroll
    for (int m = 1; m < 64; m <<= 1)
        sum += __shfl_xor(sum, m);

    if (lane == 0)
        out[edge] = bias[0] - (sum * (1.0f / 256.0f)) / temp[0];
}

extern "C" void kernel_launch(void* const* d_in, const int* in_sizes, int n_in,
                              void* d_out, int out_size, void* d_ws, size_t ws_size,
                              hipStream_t stream) {
    const float* node    = (const float*)d_in[0];
    const int*   eidx    = (const int*)  d_in[1];
    const int*   rel     = (const int*)  d_in[2];
    const float* rel_emb = (const float*)d_in[3];
    const float* temp    = (const float*)d_in[4];
    const float* bias    = (const float*)d_in[5];
    float*       out     = (float*)d_out;

    int nedges = in_sizes[1] / 2;        // edge_index is [2, nedges]
    int nnodes = in_sizes[0] / 512;      // 100000
    int nrot   = in_sizes[3];            // 64*256 = 16384

    size_t tbl_bytes = (size_t)nnodes * 768;           // 12-bit packed table
    size_t scl_bytes = (size_t)nnodes * 4;
    size_t need      = tbl_bytes + scl_bytes + (size_t)nrot * 4;

    if (ws_size >= need) {
        unsigned int* tbl = (unsigned int*)d_ws;
        float*        scl = (float*)((char*)d_ws + tbl_bytes);
        unsigned int* rot = (unsigned int*)((char*)d_ws + tbl_bytes + scl_bytes);

        build_rot_kernel<<<(nrot + 255) / 256, 256, 0, stream>>>(rel_emb, rot, nrot);

        int cblocks = (nnodes * 64 + 255) / 256;       // one wave per node row
        convert12_kernel<<<cblocks, 256, 0, stream>>>(node, tbl, scl, nnodes);

        int gblocks = (nedges * 16 + 255) / 256;       // 16 lanes per edge
        rotate_score_v4<<<gblocks, 256, 0, stream>>>(
            tbl, scl, rot, eidx, rel, temp, bias, out, nedges);
    } else {
        int eblocks = (nedges + 3) / 4;
        rotate_score_fp32<<<eblocks, 256, 0, stream>>>(
            node, eidx, rel, rel_emb, temp, bias, out, nedges);
    }
}